// Round 1
// baseline (148.202 us; speedup 1.0000x reference)
//
#include <hip/hip_runtime.h>

// ShiftMap: bicubic-upsample a 16x16x2 control shiftmap to 1024x1024x2,
// add to mesh, bicubic grid_sample (zeros padding, align_corners=True).
// Fused into a single kernel: control grid staged in LDS per block.

static constexpr float A = -0.75f;  // PyTorch bicubic coefficient

__device__ __forceinline__ void cubic_weights(float t, float* w) {
    float t2 = t * t;
    float s  = 1.0f - t;
    w[1] = (A + 2.0f) * t * t2 - (A + 3.0f) * t2 + 1.0f;       // dist = t
    w[2] = (A + 2.0f) * s * s * s - (A + 3.0f) * s * s + 1.0f; // dist = 1-t
    float u = 1.0f + t;
    w[0] = A * (u * (u * (u - 5.0f) + 8.0f) - 4.0f);           // dist = 1+t
    float v = 2.0f - t;
    w[3] = A * (v * (v * (v - 5.0f) + 8.0f) - 4.0f);           // dist = 2-t
}

__global__ __launch_bounds__(256) void shiftmap_warp_kernel(
    const float* __restrict__ img,   // (B,1,H,W)
    const float* __restrict__ smap,  // (B,CH,CW,2)
    const float* __restrict__ mesh,  // (1,H,W,2)  ch0=y, ch1=x
    float* __restrict__ out,         // (B,1,H,W)
    int H, int W, int CH, int CW)
{
    const int b = blockIdx.y;

    // Stage this batch's control grid in LDS (16*16*2 = 512 floats).
    __shared__ float s_sm[512];
    {
        const float* src = smap + (size_t)b * CH * CW * 2;
        const int n = CH * CW * 2;
        for (int i = threadIdx.x; i < n; i += blockDim.x) s_sm[i] = src[i];
    }
    __syncthreads();

    const int pix = blockIdx.x * blockDim.x + threadIdx.x;
    if (pix >= H * W) return;
    const int y = pix / W;
    const int x = pix - y * W;

    // ---- bicubic upsample of the shiftmap at (y,x), border clamp ----
    const float scale_y = (float)((double)(CH - 1) / (double)(H - 1));
    const float scale_x = (float)((double)(CW - 1) / (double)(W - 1));
    const float sy = y * scale_y;
    const float sx = x * scale_x;
    const float fy0 = floorf(sy), fx0 = floorf(sx);
    const int cy0 = (int)fy0, cx0 = (int)fx0;
    float wy[4], wx[4];
    cubic_weights(sy - fy0, wy);
    cubic_weights(sx - fx0, wx);

    float smy = 0.0f, smx = 0.0f;
    #pragma unroll
    for (int i = 0; i < 4; ++i) {
        const int cy = min(max(cy0 - 1 + i, 0), CH - 1);
        float ry = 0.0f, rx = 0.0f;
        #pragma unroll
        for (int j = 0; j < 4; ++j) {
            const int cx = min(max(cx0 - 1 + j, 0), CW - 1);
            const float* p = &s_sm[(cy * CW + cx) * 2];
            ry += wx[j] * p[0];
            rx += wx[j] * p[1];
        }
        smy += wy[i] * ry;
        smx += wy[i] * rx;
    }

    // ---- mesh + shift -> sampling coords ----
    const float my = mesh[(size_t)pix * 2 + 0];
    const float mx = mesh[(size_t)pix * 2 + 1];
    const float gy = my + smy;
    const float gx = mx + smx;

    const float ix = (gx + 1.0f) * 0.5f * (float)(W - 1);
    const float iy = (gy + 1.0f) * 0.5f * (float)(H - 1);
    const float ixf = floorf(ix), iyf = floorf(iy);
    float gwx[4], gwy[4];
    cubic_weights(ix - ixf, gwx);
    cubic_weights(iy - iyf, gwy);
    const int ix0 = (int)ixf, iy0 = (int)iyf;

    // ---- 4x4 bicubic gather, zeros padding ----
    const float* imgb = img + (size_t)b * H * W;
    float acc = 0.0f;
    #pragma unroll
    for (int i = 0; i < 4; ++i) {
        const int yy = iy0 - 1 + i;
        const bool vy = (yy >= 0) && (yy < H);
        const int yc = min(max(yy, 0), H - 1);
        const float* row = imgb + (size_t)yc * W;
        float r = 0.0f;
        #pragma unroll
        for (int j = 0; j < 4; ++j) {
            const int xx = ix0 - 1 + j;
            const bool v = vy && (xx >= 0) && (xx < W);
            const int xc = min(max(xx, 0), W - 1);
            const float val = v ? row[xc] : 0.0f;
            r += gwx[j] * val;
        }
        acc += gwy[i] * r;
    }

    out[(size_t)b * H * W + pix] = acc;
}

extern "C" void kernel_launch(void* const* d_in, const int* in_sizes, int n_in,
                              void* d_out, int out_size, void* d_ws, size_t ws_size,
                              hipStream_t stream) {
    const float* img  = (const float*)d_in[0];  // (B,1,1024,1024) fp32
    const float* smap = (const float*)d_in[1];  // (B,16,16,2) fp32
    const float* mesh = (const float*)d_in[2];  // (1,1024,1024,2) fp32
    float* out = (float*)d_out;

    const int H = 1024, W = 1024;
    const int CH = 16, CW = 16;
    const int B = in_sizes[0] / (H * W);

    dim3 block(256);
    dim3 grid((H * W + 255) / 256, B);
    shiftmap_warp_kernel<<<grid, block, 0, stream>>>(img, smap, mesh, out, H, W, CH, CW);
}

// Round 2
// 57.221 us; speedup vs baseline: 2.5900x; 2.5900x over previous
//
#include <hip/hip_runtime.h>

// ShiftMap fused kernel, v2:
//  - one block per (row y, batch b); y-interp of 16x16 control grid staged in LDS
//  - mesh computed analytically (linspace grid) and folded into pixel coords
//  - interior fast-path gather (no masks); 4 px/thread for ILP

static constexpr float A = -0.75f;  // PyTorch bicubic coefficient

__device__ __forceinline__ void cubic_weights(float t, float* w) {
    float t2 = t * t;
    float s  = 1.0f - t;
    w[1] = (A + 2.0f) * t * t2 - (A + 3.0f) * t2 + 1.0f;       // dist = t
    w[2] = (A + 2.0f) * s * s * s - (A + 3.0f) * s * s + 1.0f; // dist = 1-t
    float u = 1.0f + t;
    w[0] = A * (u * (u * (u - 5.0f) + 8.0f) - 4.0f);           // dist = 1+t
    float v = 2.0f - t;
    w[3] = A * (v * (v * (v - 5.0f) + 8.0f) - 4.0f);           // dist = 2-t
}

template <int PX_PER_THREAD>
__global__ __launch_bounds__(256) void shiftmap_warp_kernel(
    const float* __restrict__ img,   // (B,1,H,W)
    const float* __restrict__ smap,  // (B,CH,CW,2)
    float* __restrict__ out,         // (B,1,H,W)
    int H, int W, int CH, int CW)
{
    const int y   = blockIdx.x;   // image row
    const int b   = blockIdx.y;   // batch
    const int tid = threadIdx.x;

    __shared__ float s_row[64];   // CW*2 (<=64)

    const float scale_y = (float)((double)(CH - 1) / (double)(H - 1));
    const float scale_x = (float)((double)(CW - 1) / (double)(W - 1));

    // ---- stage y-interpolated control row into LDS (CW*2 values) ----
    if (tid < CW * 2) {
        const int c  = tid >> 1;
        const int ch = tid & 1;
        const float sy  = y * scale_y;
        const float fy0 = floorf(sy);
        const int   cy0 = (int)fy0;
        float wy[4];
        cubic_weights(sy - fy0, wy);
        float v = 0.0f;
        #pragma unroll
        for (int i = 0; i < 4; ++i) {
            const int cy = min(max(cy0 - 1 + i, 0), CH - 1);
            v += wy[i] * smap[(((size_t)b * CH + cy) * CW + c) * 2 + ch];
        }
        s_row[tid] = v;
    }
    __syncthreads();

    const float half_w = 0.5f * (float)(W - 1);
    const float half_h = 0.5f * (float)(H - 1);
    const float* imgb = img + (size_t)b * H * W;
    float* outb = out + (size_t)b * H * W + (size_t)y * W;

    #pragma unroll
    for (int k = 0; k < PX_PER_THREAD; ++k) {
        const int x = tid + k * 256;

        // ---- x-interp of staged control row -> (smy, smx) ----
        const float sx  = x * scale_x;
        const float fx0 = floorf(sx);
        const int   cx0 = (int)fx0;
        float wx[4];
        cubic_weights(sx - fx0, wx);
        float smy = 0.0f, smx = 0.0f;
        #pragma unroll
        for (int j = 0; j < 4; ++j) {
            const int cx = min(max(cx0 - 1 + j, 0), CW - 1);
            smy += wx[j] * s_row[cx * 2 + 0];
            smx += wx[j] * s_row[cx * 2 + 1];
        }

        // ---- sampling coords (mesh folded analytically) ----
        const float ix = (float)x + smx * half_w;
        const float iy = (float)y + smy * half_h;
        const float ixf = floorf(ix), iyf = floorf(iy);
        const int ix0 = (int)ixf, iy0 = (int)iyf;
        float gwx[4], gwy[4];
        cubic_weights(ix - ixf, gwx);
        cubic_weights(iy - iyf, gwy);

        // ---- 4x4 bicubic gather ----
        float acc = 0.0f;
        if (ix0 >= 1 && ix0 <= W - 3 && iy0 >= 1 && iy0 <= H - 3) {
            // interior fast path: all 16 taps in-bounds, no masks
            const float* p = imgb + (size_t)(iy0 - 1) * W + (ix0 - 1);
            #pragma unroll
            for (int i = 0; i < 4; ++i) {
                const float r = gwx[0] * p[0] + gwx[1] * p[1]
                              + gwx[2] * p[2] + gwx[3] * p[3];
                acc += gwy[i] * r;
                p += W;
            }
        } else {
            // border: zeros padding with per-tap masks
            #pragma unroll
            for (int i = 0; i < 4; ++i) {
                const int yy = iy0 - 1 + i;
                const bool vy = (yy >= 0) && (yy < H);
                const int yc = min(max(yy, 0), H - 1);
                const float* row = imgb + (size_t)yc * W;
                float r = 0.0f;
                #pragma unroll
                for (int j = 0; j < 4; ++j) {
                    const int xx = ix0 - 1 + j;
                    const bool v = vy && (xx >= 0) && (xx < W);
                    const int xc = min(max(xx, 0), W - 1);
                    r += gwx[j] * (v ? row[xc] : 0.0f);
                }
                acc += gwy[i] * r;
            }
        }
        outb[x] = acc;
    }
}

extern "C" void kernel_launch(void* const* d_in, const int* in_sizes, int n_in,
                              void* d_out, int out_size, void* d_ws, size_t ws_size,
                              hipStream_t stream) {
    const float* img  = (const float*)d_in[0];  // (B,1,1024,1024) fp32
    const float* smap = (const float*)d_in[1];  // (B,16,16,2) fp32
    float* out = (float*)d_out;

    const int H = 1024, W = 1024;
    const int CH = 16, CW = 16;
    const int B = in_sizes[0] / (H * W);

    // one block per (row, batch); 256 threads x 4 px = 1024 px = one row
    dim3 block(256);
    dim3 grid(H, B);
    shiftmap_warp_kernel<4><<<grid, block, 0, stream>>>(img, smap, out, H, W, CH, CW);
}

// Round 3
// 47.903 us; speedup vs baseline: 3.0938x; 1.1945x over previous
//
#include <hip/hip_runtime.h>

// ShiftMap fused kernel, v3:
//  - v2 + XCD-aware block swizzle: 1D grid; XCD k owns a contiguous band of
//    (batch,row) work (B=8 -> one batch per XCD, 4MB image fits one L2).
//  - one block per (row, batch); y-interp of control grid staged in LDS
//  - mesh folded analytically; interior fast-path gather; 4 px/thread

static constexpr float A = -0.75f;  // PyTorch bicubic coefficient
static constexpr int NXCD = 8;

__device__ __forceinline__ void cubic_weights(float t, float* w) {
    float t2 = t * t;
    float s  = 1.0f - t;
    w[1] = (A + 2.0f) * t * t2 - (A + 3.0f) * t2 + 1.0f;       // dist = t
    w[2] = (A + 2.0f) * s * s * s - (A + 3.0f) * s * s + 1.0f; // dist = 1-t
    float u = 1.0f + t;
    w[0] = A * (u * (u * (u - 5.0f) + 8.0f) - 4.0f);           // dist = 1+t
    float v = 2.0f - t;
    w[3] = A * (v * (v * (v - 5.0f) + 8.0f) - 4.0f);           // dist = 2-t
}

template <int PX_PER_THREAD>
__global__ __launch_bounds__(256) void shiftmap_warp_kernel(
    const float* __restrict__ img,   // (B,1,H,W)
    const float* __restrict__ smap,  // (B,CH,CW,2)
    float* __restrict__ out,         // (B,1,H,W)
    int H, int W, int CH, int CW, int nblocks)
{
    // ---- XCD-aware swizzle: round-robin dispatch -> contiguous work bands ----
    // dispatch id d lands on XCD d%8; give XCD k work [k*per, (k+1)*per).
    const int d   = blockIdx.x;
    const int per = nblocks / NXCD;           // nblocks % 8 == 0 here (8192)
    const int work = (d % NXCD) * per + d / NXCD;
    const int y = work % H;                    // image row
    const int b = work / H;                    // batch
    const int tid = threadIdx.x;

    __shared__ float s_row[64];   // CW*2 (<=64)

    const float scale_y = (float)((double)(CH - 1) / (double)(H - 1));
    const float scale_x = (float)((double)(CW - 1) / (double)(W - 1));

    // ---- stage y-interpolated control row into LDS (CW*2 values) ----
    if (tid < CW * 2) {
        const int c  = tid >> 1;
        const int ch = tid & 1;
        const float sy  = y * scale_y;
        const float fy0 = floorf(sy);
        const int   cy0 = (int)fy0;
        float wy[4];
        cubic_weights(sy - fy0, wy);
        float v = 0.0f;
        #pragma unroll
        for (int i = 0; i < 4; ++i) {
            const int cy = min(max(cy0 - 1 + i, 0), CH - 1);
            v += wy[i] * smap[(((size_t)b * CH + cy) * CW + c) * 2 + ch];
        }
        s_row[tid] = v;
    }
    __syncthreads();

    const float half_w = 0.5f * (float)(W - 1);
    const float half_h = 0.5f * (float)(H - 1);
    const float* imgb = img + (size_t)b * H * W;
    float* outb = out + (size_t)b * H * W + (size_t)y * W;

    #pragma unroll
    for (int k = 0; k < PX_PER_THREAD; ++k) {
        const int x = tid + k * 256;

        // ---- x-interp of staged control row -> (smy, smx) ----
        const float sx  = x * scale_x;
        const float fx0 = floorf(sx);
        const int   cx0 = (int)fx0;
        float wx[4];
        cubic_weights(sx - fx0, wx);
        float smy = 0.0f, smx = 0.0f;
        #pragma unroll
        for (int j = 0; j < 4; ++j) {
            const int cx = min(max(cx0 - 1 + j, 0), CW - 1);
            smy += wx[j] * s_row[cx * 2 + 0];
            smx += wx[j] * s_row[cx * 2 + 1];
        }

        // ---- sampling coords (mesh folded analytically) ----
        const float ix = (float)x + smx * half_w;
        const float iy = (float)y + smy * half_h;
        const float ixf = floorf(ix), iyf = floorf(iy);
        const int ix0 = (int)ixf, iy0 = (int)iyf;
        float gwx[4], gwy[4];
        cubic_weights(ix - ixf, gwx);
        cubic_weights(iy - iyf, gwy);

        // ---- 4x4 bicubic gather ----
        float acc = 0.0f;
        if (ix0 >= 1 && ix0 <= W - 3 && iy0 >= 1 && iy0 <= H - 3) {
            // interior fast path: all 16 taps in-bounds, no masks
            const float* p = imgb + (size_t)(iy0 - 1) * W + (ix0 - 1);
            #pragma unroll
            for (int i = 0; i < 4; ++i) {
                const float r = gwx[0] * p[0] + gwx[1] * p[1]
                              + gwx[2] * p[2] + gwx[3] * p[3];
                acc += gwy[i] * r;
                p += W;
            }
        } else {
            // border: zeros padding with per-tap masks
            #pragma unroll
            for (int i = 0; i < 4; ++i) {
                const int yy = iy0 - 1 + i;
                const bool vy = (yy >= 0) && (yy < H);
                const int yc = min(max(yy, 0), H - 1);
                const float* row = imgb + (size_t)yc * W;
                float r = 0.0f;
                #pragma unroll
                for (int j = 0; j < 4; ++j) {
                    const int xx = ix0 - 1 + j;
                    const bool v = vy && (xx >= 0) && (xx < W);
                    const int xc = min(max(xx, 0), W - 1);
                    r += gwx[j] * (v ? row[xc] : 0.0f);
                }
                acc += gwy[i] * r;
            }
        }
        outb[x] = acc;
    }
}

extern "C" void kernel_launch(void* const* d_in, const int* in_sizes, int n_in,
                              void* d_out, int out_size, void* d_ws, size_t ws_size,
                              hipStream_t stream) {
    const float* img  = (const float*)d_in[0];  // (B,1,1024,1024) fp32
    const float* smap = (const float*)d_in[1];  // (B,16,16,2) fp32
    float* out = (float*)d_out;

    const int H = 1024, W = 1024;
    const int CH = 16, CW = 16;
    const int B = in_sizes[0] / (H * W);
    const int nblocks = H * B;   // one block per (row, batch); 8192 (mult of 8)

    dim3 block(256);
    dim3 grid(nblocks);
    shiftmap_warp_kernel<4><<<grid, block, 0, stream>>>(img, smap, out, H, W, CH, CW, nblocks);
}